// Round 1
// baseline (132.556 us; speedup 1.0000x reference)
//
#include <hip/hip_runtime.h>
#include <hip/hip_bf16.h>

#define N_PTS 20000
#define NSAMP 32
#define CIN 64
#define COUT 128
#define M_ROWS (N_PTS * NSAMP)   // 640000 rows
#define TILES (M_ROWS / 64)      // 10000 64-row tiles
#define K1_BLOCKS 512
#define K1_WAVES (K1_BLOCKS * 4) // 2048
#define BN_EPS 1e-5f

typedef __attribute__((ext_vector_type(8))) short short8v;
typedef __attribute__((ext_vector_type(4))) float f32x4;

// float -> bf16 bits, round-to-nearest-even (no type-punning headaches)
__device__ inline short bf16_of(float f) {
    unsigned u = __float_as_uint(f);
    u = (u + 0x7FFFu + ((u >> 16) & 1u)) >> 16;
    return (short)u;
}

// ---------------------------------------------------------------------------
// Kernel 1: per-block partials of S = F^T F (64x64) and colsum(F) (64)
// Each wave streams 64-row tiles; MFMA 16x16x32 bf16 computes all 16 output
// tiles of the 64x64 Gram matrix. A-frag == B-frag data (same per-lane k
// mapping) -> result invariant to the hardware k-permutation.
// ---------------------------------------------------------------------------
__global__ __launch_bounds__(256) void k1_stats(const float* __restrict__ F,
                                                float* __restrict__ Sp,
                                                float* __restrict__ Cp) {
    const int tid = threadIdx.x;
    const int wid = tid >> 6;
    const int lane = tid & 63;
    const int g = lane >> 4;
    const int i = lane & 15;
    const int gw = blockIdx.x * 4 + wid;

    f32x4 acc[4][4];
#pragma unroll
    for (int a = 0; a < 4; ++a)
#pragma unroll
        for (int b = 0; b < 4; ++b)
            acc[a][b] = (f32x4){0.f, 0.f, 0.f, 0.f};
    float colp[4] = {0.f, 0.f, 0.f, 0.f};

    for (int tile = gw; tile < TILES; tile += K1_WAVES) {
        const float* fb = F + (size_t)tile * 4096;
        short8v frag[4][2];
#pragma unroll
        for (int jt = 0; jt < 4; ++jt) {
            float cs = 0.f;
#pragma unroll
            for (int kk = 0; kk < 2; ++kk) {
                short8v fr;
#pragma unroll
                for (int r = 0; r < 8; ++r) {
                    float v = fb[(kk * 32 + g * 8 + r) * 64 + jt * 16 + i];
                    cs += v;
                    fr[r] = bf16_of(v);
                }
                frag[jt][kk] = fr;
            }
            colp[jt] += cs;
        }
#pragma unroll
        for (int it = 0; it < 4; ++it)
#pragma unroll
            for (int jt = 0; jt < 4; ++jt) {
                acc[it][jt] = __builtin_amdgcn_mfma_f32_16x16x32_bf16(
                    frag[it][0], frag[jt][0], acc[it][jt], 0, 0, 0);
                acc[it][jt] = __builtin_amdgcn_mfma_f32_16x16x32_bf16(
                    frag[it][1], frag[jt][1], acc[it][jt], 0, 0, 0);
            }
    }

    // colsum: reduce the 4 lane-groups (g) holding the same column
#pragma unroll
    for (int jt = 0; jt < 4; ++jt) {
        colp[jt] += __shfl_xor(colp[jt], 16);
        colp[jt] += __shfl_xor(colp[jt], 32);
    }
    if (lane < 16) {
#pragma unroll
        for (int jt = 0; jt < 4; ++jt)
            Cp[gw * 64 + jt * 16 + lane] = colp[jt];
    }

    // block-level reduction of the 4 waves' S partials via LDS
    __shared__ float sS[4096];
    for (int w = 0; w < 4; ++w) {
        if (wid == w) {
#pragma unroll
            for (int it = 0; it < 4; ++it)
#pragma unroll
                for (int jt = 0; jt < 4; ++jt)
#pragma unroll
                    for (int r = 0; r < 4; ++r) {
                        // C/D layout: col = lane&15, row = (lane>>4)*4 + reg
                        int idx = (it * 16 + g * 4 + r) * 64 + jt * 16 + i;
                        if (w == 0) sS[idx] = acc[it][jt][r];
                        else        sS[idx] += acc[it][jt][r];
                    }
        }
        __syncthreads();
    }
    float4* dst = (float4*)(Sp + (size_t)blockIdx.x * 4096);
    const float4* src = (const float4*)sS;
#pragma unroll
    for (int q = 0; q < 4; ++q)
        dst[q * 256 + tid] = src[q * 256 + tid];
}

// ---------------------------------------------------------------------------
// Kernel 1b: reduce per-block partials -> S[4096], colsum[64]
// ---------------------------------------------------------------------------
__global__ __launch_bounds__(64) void k1_reduce(const float* __restrict__ Sp,
                                                const float* __restrict__ Cp,
                                                float* __restrict__ S,
                                                float* __restrict__ colsum) {
    int o = blockIdx.x * 64 + threadIdx.x;
    if (o < 4096) {
        float s = 0.f;
        for (int b = 0; b < K1_BLOCKS; ++b) s += Sp[(size_t)b * 4096 + o];
        S[o] = s;
    } else if (o < 4160) {
        int c = o - 4096;
        float s = 0.f;
        for (int w = 0; w < K1_WAVES; ++w) s += Cp[w * 64 + c];
        colsum[c] = s;
    }
}

// ---------------------------------------------------------------------------
// Kernel 1c: BN affine constants.  mu_d = (W_d . colsum)/M,
// E[x^2]_d = (W_d^T S W_d)/M, scale = gamma*rsqrt(var+eps), shift = beta-mu*scale
// One block (1 wave) per output channel d.
// ---------------------------------------------------------------------------
__global__ __launch_bounds__(64) void k1_scales(const float* __restrict__ S,
                                                const float* __restrict__ colsum,
                                                const float* __restrict__ W,
                                                const float* __restrict__ gamma,
                                                const float* __restrict__ beta,
                                                float* __restrict__ scale,
                                                float* __restrict__ shift) {
    int d = blockIdx.x;
    int tid = threadIdx.x;
    __shared__ float w[64];
    w[tid] = W[d * 64 + tid];
    __syncthreads();
    float wi = w[tid];
    float rowdot = 0.f;
#pragma unroll
    for (int j = 0; j < 64; ++j) rowdot += S[tid * 64 + j] * w[j];
    float p = wi * rowdot;
    float mup = wi * colsum[tid];
    for (int k = 1; k <= 32; k <<= 1) {
        p += __shfl_xor(p, k);
        mup += __shfl_xor(mup, k);
    }
    if (tid == 0) {
        const float invM = 1.f / (float)M_ROWS;
        float mu = mup * invM;
        float ex2 = p * invM;
        float var = ex2 - mu * mu;
        float rs = rsqrtf(var + BN_EPS);
        float sc = gamma[d] * rs;
        scale[d] = sc;
        shift[d] = beta[d] - mu * sc;
    }
}

// ---------------------------------------------------------------------------
// Kernel 2: fused GEMM (bf16 MFMA) + BN affine + ReLU + geo-weighted masked
// mean-pool.  One wave handles 4 consecutive points n; W fragments live in
// registers; per-wave geo buffer in LDS; no __syncthreads needed.
// ---------------------------------------------------------------------------
__global__ __launch_bounds__(256) void k2_main(const float* __restrict__ F,
                                               const float* __restrict__ coords,
                                               const float* __restrict__ centers,
                                               const int* __restrict__ mask,
                                               const float* __restrict__ W,
                                               const float* __restrict__ scale,
                                               const float* __restrict__ shift,
                                               float* __restrict__ out) {
    const int tid = threadIdx.x;
    const int wid = tid >> 6;
    const int lane = tid & 63;
    const int g = lane >> 4;
    const int i = lane & 15;
    const int n_base = (blockIdx.x * 4 + wid) * 4;

    // B fragments (W^T), register-resident: b[t][kk], t = d-tile, kk = k-step
    short8v b[8][2];
#pragma unroll
    for (int t = 0; t < 8; ++t)
#pragma unroll
        for (int kk = 0; kk < 2; ++kk) {
            const float* wp = W + (t * 16 + i) * 64 + kk * 32 + g * 8;
            short8v fr;
#pragma unroll
            for (int r = 0; r < 8; ++r) fr[r] = bf16_of(wp[r]);
            b[t][kk] = fr;
        }
    float sc[8], sh[8];
#pragma unroll
    for (int t = 0; t < 8; ++t) {
        sc[t] = scale[t * 16 + i];
        sh[t] = shift[t * 16 + i];
    }

    __shared__ float geoM[4][32][4];  // per-wave private
    const f32x4 Z = {0.f, 0.f, 0.f, 0.f};

    for (int it = 0; it < 4; ++it) {
        const int n = n_base + it;

        // geo phase: lanes 0..31 each own one neighbor s
        float m = 0.f;
        if (lane < 32) {
            const int s = lane;
            const float* cp = coords + ((size_t)n * NSAMP + s) * 3;
            float r0 = cp[0] - centers[n * 4 + 1];
            float r1 = cp[1] - centers[n * 4 + 2];
            float r2 = cp[2] - centers[n * 4 + 3];
            float dist = r0 * r0 + r1 * r1 + r2 * r2;
            m = (float)mask[n * NSAMP + s];
            float4 gm = make_float4(r0 * 10.f * m, r1 * 10.f * m,
                                    r2 * 5.f * m, dist * (1.f / 0.06f) * m);
            *(float4*)&geoM[wid][s][0] = gm;
        }
        float den = m;
        for (int k = 1; k <= 32; k <<= 1) den += __shfl_xor(den, k);
        float inv_den = 1.f / fmaxf(den, 1.f);

        // A fragments: features rows of this point
        short8v a[2][2];
#pragma unroll
        for (int mt = 0; mt < 2; ++mt)
#pragma unroll
            for (int kk = 0; kk < 2; ++kk) {
                const float* fp =
                    F + ((size_t)n * NSAMP + mt * 16 + i) * 64 + kk * 32 + g * 8;
                short8v fr;
#pragma unroll
                for (int r = 0; r < 8; ++r) fr[r] = bf16_of(fp[r]);
                a[mt][kk] = fr;
            }

        // keep compiler from moving the geo reads above the geo store
        __builtin_amdgcn_sched_barrier(0);

        // per-lane geo weights for the 8 rows this lane's C covers
        float gv[2][4];
        const int j0 = i & 3;  // d % 4
#pragma unroll
        for (int mt = 0; mt < 2; ++mt)
#pragma unroll
            for (int r = 0; r < 4; ++r)
                gv[mt][r] = geoM[wid][mt * 16 + g * 4 + r][j0];

#pragma unroll
        for (int t = 0; t < 8; ++t) {
            float nump = 0.f;
#pragma unroll
            for (int mt = 0; mt < 2; ++mt) {
                f32x4 acc = __builtin_amdgcn_mfma_f32_16x16x32_bf16(
                    a[mt][0], b[t][0], Z, 0, 0, 0);
                acc = __builtin_amdgcn_mfma_f32_16x16x32_bf16(
                    a[mt][1], b[t][1], acc, 0, 0, 0);
#pragma unroll
                for (int r = 0; r < 4; ++r) {
                    float v = fmaf(acc[r], sc[t], sh[t]);
                    v = fmaxf(v, 0.f);
                    nump = fmaf(v, gv[mt][r], nump);
                }
            }
            nump += __shfl_xor(nump, 16);
            nump += __shfl_xor(nump, 32);
            if (lane < 16)
                out[(size_t)n * COUT + t * 16 + lane] = nump * inv_den;
        }
    }
}

// ---------------------------------------------------------------------------
extern "C" void kernel_launch(void* const* d_in, const int* in_sizes, int n_in,
                              void* d_out, int out_size, void* d_ws, size_t ws_size,
                              hipStream_t stream) {
    const float* F = (const float*)d_in[0];
    const float* coords = (const float*)d_in[1];
    const float* centers = (const float*)d_in[2];
    const int* mask = (const int*)d_in[3];
    const float* W = (const float*)d_in[4];
    const float* gamma = (const float*)d_in[5];
    const float* beta = (const float*)d_in[6];
    float* out = (float*)d_out;

    float* wsf = (float*)d_ws;
    float* scale = wsf;                      // 128
    float* shift = wsf + 128;                // 128
    float* S = wsf + 256;                    // 4096
    float* colsum = wsf + 4352;              // 64
    float* Sp = wsf + 4608;                  // K1_BLOCKS*4096
    float* Cp = Sp + (size_t)K1_BLOCKS * 4096;  // K1_WAVES*64

    k1_stats<<<K1_BLOCKS, 256, 0, stream>>>(F, Sp, Cp);
    k1_reduce<<<65, 64, 0, stream>>>(Sp, Cp, S, colsum);
    k1_scales<<<COUT, 64, 0, stream>>>(S, colsum, W, gamma, beta, scale, shift);
    k2_main<<<1250, 256, 0, stream>>>(F, coords, centers, mask, W, scale, shift, out);
}

// Round 2
// 94.015 us; speedup vs baseline: 1.4099x; 1.4099x over previous
//
#include <hip/hip_runtime.h>
#include <hip/hip_bf16.h>

#define N_PTS 20000
#define NSAMP 32
#define CIN 64
#define COUT 128
#define M_ROWS (N_PTS * NSAMP)   // 640000 rows
#define TILES (M_ROWS / 64)      // 10000 64-row tiles
#define K1_BLOCKS 1024
#define K1_WAVES (K1_BLOCKS * 4) // 4096
#define BN_EPS 1e-5f

typedef __attribute__((ext_vector_type(8))) short short8v;
typedef __attribute__((ext_vector_type(4))) float f32x4;

// float -> bf16 bits, round-to-nearest-even
__device__ inline short bf16_of(float f) {
    unsigned u = __float_as_uint(f);
    u = (u + 0x7FFFu + ((u >> 16) & 1u)) >> 16;
    return (short)u;
}

// ---------------------------------------------------------------------------
// Kernel 1: per-block partials of S = F^T F (64x64) and colsum(F) (64).
// A-frag == B-frag data (same per-lane k mapping) -> k-permutation cancels.
// ---------------------------------------------------------------------------
__global__ __launch_bounds__(256) void k1_stats(const float* __restrict__ F,
                                                float* __restrict__ Sp,
                                                float* __restrict__ Cp) {
    const int tid = threadIdx.x;
    const int wid = tid >> 6;
    const int lane = tid & 63;
    const int g = lane >> 4;
    const int i = lane & 15;
    const int gw = blockIdx.x * 4 + wid;

    f32x4 acc[4][4];
#pragma unroll
    for (int a = 0; a < 4; ++a)
#pragma unroll
        for (int b = 0; b < 4; ++b)
            acc[a][b] = (f32x4){0.f, 0.f, 0.f, 0.f};
    float colp[4] = {0.f, 0.f, 0.f, 0.f};

    for (int tile = gw; tile < TILES; tile += K1_WAVES) {
        // per-lane bases; all loads below are base + small const offset
        const float* fb0 = F + (size_t)tile * 4096 + g * 512 + i;  // kk=0
        const float* fb1 = fb0 + 2048;                              // kk=1
        short8v frag[4][2];
#pragma unroll
        for (int jt = 0; jt < 4; ++jt) {
            float cs = 0.f;
#pragma unroll
            for (int kk = 0; kk < 2; ++kk) {
                const float* p = kk ? fb1 : fb0;
                short8v fr;
#pragma unroll
                for (int r = 0; r < 8; ++r) {
                    float v = p[r * 64 + jt * 16];
                    cs += v;
                    fr[r] = bf16_of(v);
                }
                frag[jt][kk] = fr;
            }
            colp[jt] += cs;
        }
#pragma unroll
        for (int it = 0; it < 4; ++it)
#pragma unroll
            for (int jt = 0; jt < 4; ++jt) {
                acc[it][jt] = __builtin_amdgcn_mfma_f32_16x16x32_bf16(
                    frag[it][0], frag[jt][0], acc[it][jt], 0, 0, 0);
                acc[it][jt] = __builtin_amdgcn_mfma_f32_16x16x32_bf16(
                    frag[it][1], frag[jt][1], acc[it][jt], 0, 0, 0);
            }
    }

    // colsum: combine the 4 lane-groups holding the same column
#pragma unroll
    for (int jt = 0; jt < 4; ++jt) {
        colp[jt] += __shfl_xor(colp[jt], 16);
        colp[jt] += __shfl_xor(colp[jt], 32);
    }
    if (lane < 16) {
#pragma unroll
        for (int jt = 0; jt < 4; ++jt)
            Cp[gw * 64 + jt * 16 + lane] = colp[jt];
    }

    // block-level reduction of the 4 waves' S partials via LDS
    __shared__ float sS[4096];
    for (int w = 0; w < 4; ++w) {
        if (wid == w) {
#pragma unroll
            for (int it = 0; it < 4; ++it)
#pragma unroll
                for (int jt = 0; jt < 4; ++jt)
#pragma unroll
                    for (int r = 0; r < 4; ++r) {
                        // C/D layout: col = lane&15, row = (lane>>4)*4 + reg
                        int idx = (it * 16 + g * 4 + r) * 64 + jt * 16 + i;
                        if (w == 0) sS[idx] = acc[it][jt][r];
                        else        sS[idx] += acc[it][jt][r];
                    }
        }
        __syncthreads();
    }
    float4* dst = (float4*)(Sp + (size_t)blockIdx.x * 4096);
    const float4* src = (const float4*)sS;
#pragma unroll
    for (int q = 0; q < 4; ++q)
        dst[q * 256 + tid] = src[q * 256 + tid];
}

// ---------------------------------------------------------------------------
// Reduce stage A: shallow (depth-64) partial reduction.
//   S:      4096 elems x 16 chunks, chunk sums 64 of the 1024 block partials
//   colsum: 64 elems x 64 chunks, chunk sums 64 of the 4096 wave partials
// ---------------------------------------------------------------------------
__global__ __launch_bounds__(256) void k1_reduceA(const float* __restrict__ Sp,
                                                  const float* __restrict__ Cp,
                                                  float* __restrict__ Tp,
                                                  float* __restrict__ Tcp) {
    int t = blockIdx.x * 256 + threadIdx.x;
    if (t < 65536) {
        int o = t & 4095;
        int c = t >> 12;
        float s = 0.f;
#pragma unroll 8
        for (int b = 0; b < 64; ++b)
            s += Sp[(size_t)(c * 64 + b) * 4096 + o];
        Tp[t] = s;  // Tp[c*4096 + o]
    } else if (t < 65536 + 4096) {
        int u = t - 65536;
        int col = u & 63;
        int c = u >> 6;
        float s = 0.f;
#pragma unroll 8
        for (int w = 0; w < 64; ++w)
            s += Cp[(c * 64 + w) * 64 + col];
        Tcp[u] = s;  // Tcp[c*64 + col]
    }
}

// Reduce stage B: 16 (or 64) chunk partials -> final S, colsum
__global__ __launch_bounds__(256) void k1_reduceB(const float* __restrict__ Tp,
                                                  const float* __restrict__ Tcp,
                                                  float* __restrict__ S,
                                                  float* __restrict__ colsum) {
    int t = blockIdx.x * 256 + threadIdx.x;
    if (t < 4096) {
        float s = 0.f;
#pragma unroll
        for (int c = 0; c < 16; ++c) s += Tp[c * 4096 + t];
        S[t] = s;
    } else if (t < 4160) {
        int col = t - 4096;
        float s = 0.f;
#pragma unroll
        for (int c = 0; c < 64; ++c) s += Tcp[c * 64 + col];
        colsum[col] = s;
    }
}

// ---------------------------------------------------------------------------
// BN affine constants.  mu_d = (W_d . colsum)/M, E[x^2]_d = (W_d^T S W_d)/M
// ---------------------------------------------------------------------------
__global__ __launch_bounds__(64) void k1_scales(const float* __restrict__ S,
                                                const float* __restrict__ colsum,
                                                const float* __restrict__ W,
                                                const float* __restrict__ gamma,
                                                const float* __restrict__ beta,
                                                float* __restrict__ scale,
                                                float* __restrict__ shift) {
    int d = blockIdx.x;
    int tid = threadIdx.x;
    __shared__ float w[64];
    w[tid] = W[d * 64 + tid];
    __syncthreads();
    float wi = w[tid];
    float rowdot = 0.f;
#pragma unroll
    for (int j = 0; j < 64; ++j) rowdot += S[tid * 64 + j] * w[j];
    float p = wi * rowdot;
    float mup = wi * colsum[tid];
    for (int k = 1; k <= 32; k <<= 1) {
        p += __shfl_xor(p, k);
        mup += __shfl_xor(mup, k);
    }
    if (tid == 0) {
        const float invM = 1.f / (float)M_ROWS;
        float mu = mup * invM;
        float ex2 = p * invM;
        float var = ex2 - mu * mu;
        float rs = rsqrtf(var + BN_EPS);
        float sc = gamma[d] * rs;
        scale[d] = sc;
        shift[d] = beta[d] - mu * sc;
    }
}

// ---------------------------------------------------------------------------
// Kernel 2: fused GEMM (bf16 MFMA) + BN affine + ReLU + geo-weighted masked
// mean-pool.  One wave per 4 points; W fragments register-resident; per-wave
// geo buffer in LDS; DS-only sched pin so VMEM/MFMA can overlap freely.
// ---------------------------------------------------------------------------
__global__ __launch_bounds__(256) void k2_main(const float* __restrict__ F,
                                               const float* __restrict__ coords,
                                               const float* __restrict__ centers,
                                               const int* __restrict__ mask,
                                               const float* __restrict__ W,
                                               const float* __restrict__ scale,
                                               const float* __restrict__ shift,
                                               float* __restrict__ out) {
    const int tid = threadIdx.x;
    const int wid = tid >> 6;
    const int lane = tid & 63;
    const int g = lane >> 4;
    const int i = lane & 15;
    const int n_base = (blockIdx.x * 4 + wid) * 4;

    // B fragments (W^T), register-resident
    short8v b[8][2];
#pragma unroll
    for (int t = 0; t < 8; ++t)
#pragma unroll
        for (int kk = 0; kk < 2; ++kk) {
            const float* wp = W + (t * 16 + i) * 64 + kk * 32 + g * 8;
            short8v fr;
#pragma unroll
            for (int r = 0; r < 8; ++r) fr[r] = bf16_of(wp[r]);
            b[t][kk] = fr;
        }
    float sc[8], sh[8];
#pragma unroll
    for (int t = 0; t < 8; ++t) {
        sc[t] = scale[t * 16 + i];
        sh[t] = shift[t * 16 + i];
    }

    __shared__ float geoM[4][32][4];  // per-wave private
    const f32x4 Z = {0.f, 0.f, 0.f, 0.f};

    for (int it = 0; it < 4; ++it) {
        const int n = n_base + it;

        // A fragments first: contiguous 8-float runs -> dwordx4 loads,
        // issued early so they are in flight during the geo phase.
        short8v a[2][2];
#pragma unroll
        for (int mt = 0; mt < 2; ++mt)
#pragma unroll
            for (int kk = 0; kk < 2; ++kk) {
                const float* fp =
                    F + ((size_t)n * NSAMP + mt * 16 + i) * 64 + kk * 32 + g * 8;
                short8v fr;
#pragma unroll
                for (int r = 0; r < 8; ++r) fr[r] = bf16_of(fp[r]);
                a[mt][kk] = fr;
            }

        // geo phase: lanes 0..31 each own one neighbor s
        float m = 0.f;
        if (lane < 32) {
            const int s = lane;
            const float* cp = coords + ((size_t)n * NSAMP + s) * 3;
            float r0 = cp[0] - centers[n * 4 + 1];
            float r1 = cp[1] - centers[n * 4 + 2];
            float r2 = cp[2] - centers[n * 4 + 3];
            float dist = r0 * r0 + r1 * r1 + r2 * r2;
            m = (float)mask[n * NSAMP + s];
            float4 gm = make_float4(r0 * 10.f * m, r1 * 10.f * m,
                                    r2 * 5.f * m, dist * (1.f / 0.06f) * m);
            *(float4*)&geoM[wid][s][0] = gm;
        }
        float den = m;
        for (int k = 1; k <= 32; k <<= 1) den += __shfl_xor(den, k);
        float inv_den = 1.f / fmaxf(den, 1.f);

        // pin only DS ops (write above vs reads below); ALU/VMEM/MFMA may cross
        __builtin_amdgcn_sched_barrier(0x7F);

        // per-lane geo weights for the 8 rows this lane's C covers
        float gv[2][4];
        const int j0 = i & 3;  // d % 4
#pragma unroll
        for (int mt = 0; mt < 2; ++mt)
#pragma unroll
            for (int r = 0; r < 4; ++r)
                gv[mt][r] = geoM[wid][mt * 16 + g * 4 + r][j0];

#pragma unroll
        for (int t = 0; t < 8; ++t) {
            float nump = 0.f;
#pragma unroll
            for (int mt = 0; mt < 2; ++mt) {
                f32x4 acc = __builtin_amdgcn_mfma_f32_16x16x32_bf16(
                    a[mt][0], b[t][0], Z, 0, 0, 0);
                acc = __builtin_amdgcn_mfma_f32_16x16x32_bf16(
                    a[mt][1], b[t][1], acc, 0, 0, 0);
#pragma unroll
                for (int r = 0; r < 4; ++r) {
                    float v = fmaf(acc[r], sc[t], sh[t]);
                    v = fmaxf(v, 0.f);
                    nump = fmaf(v, gv[mt][r], nump);
                }
            }
            nump += __shfl_xor(nump, 16);
            nump += __shfl_xor(nump, 32);
            if (lane < 16)
                out[(size_t)n * COUT + t * 16 + lane] = nump * inv_den;
        }
    }
}

// ---------------------------------------------------------------------------
extern "C" void kernel_launch(void* const* d_in, const int* in_sizes, int n_in,
                              void* d_out, int out_size, void* d_ws, size_t ws_size,
                              hipStream_t stream) {
    const float* F = (const float*)d_in[0];
    const float* coords = (const float*)d_in[1];
    const float* centers = (const float*)d_in[2];
    const int* mask = (const int*)d_in[3];
    const float* W = (const float*)d_in[4];
    const float* gamma = (const float*)d_in[5];
    const float* beta = (const float*)d_in[6];
    float* out = (float*)d_out;

    float* wsf = (float*)d_ws;
    float* scale = wsf;                        // 128
    float* shift = wsf + 128;                  // 128
    float* S = wsf + 256;                      // 4096
    float* colsum = wsf + 4352;                // 64
    float* Tp = wsf + 4416;                    // 65536
    float* Tcp = Tp + 65536;                   // 4096
    float* Sp = Tcp + 4096;                    // K1_BLOCKS*4096
    float* Cp = Sp + (size_t)K1_BLOCKS * 4096; // K1_WAVES*64

    k1_stats<<<K1_BLOCKS, 256, 0, stream>>>(F, Sp, Cp);
    k1_reduceA<<<272, 256, 0, stream>>>(Sp, Cp, Tp, Tcp);
    k1_reduceB<<<17, 256, 0, stream>>>(Tp, Tcp, S, colsum);
    k1_scales<<<COUT, 64, 0, stream>>>(S, colsum, W, gamma, beta, scale, shift);
    k2_main<<<1250, 256, 0, stream>>>(F, coords, centers, mask, W, scale, shift, out);
}